// Round 1
// baseline (103.107 us; speedup 1.0000x reference)
//
#include <hip/hip_runtime.h>
#include <math.h>

#ifndef M_PI
#define M_PI 3.14159265358979323846
#endif

// Problem constants (from reference)
namespace {
constexpr int kL = 2048;          // sequence length
constexpr int kB = 16;            // batch
constexpr int kVocab = 10;
constexpr int kTPerBlock = 4;     // one query t per wave, 4 waves per block
constexpr int kBlock = 256;
}

// Derivation (see reference):
//   h(d)  = (c - eps*d^2, -d)                          -- token-only
//   hn    = h * rsqrt(mean(h^2)+1e-6)
//   r     = hn0 * rsqrt(hn0^2/2 + 1e-6)                -- shared by q,k after their rms_norms
//   score(t,s) = ATTN_SCALE * r_t * r_s * cos(omega*(s-t)+phi)
//              = qc(t)*Kc(s) + qs(t)*Ks(s)
//   with qc=S*r_t*cos(omega*t), qs=S*r_t*sin(omega*t),
//        Kc=r_s*cos(omega*s+phi), Ks=r_s*sin(omega*s+phi)
//   omega = 2*pi/19  => all angles reduced exactly via (idx % 19).
//   attn_out0(t) = softmax_s(score) . (hn1(s)*v)

__global__ __launch_bounds__(kBlock)
void fused_kernel(const int* __restrict__ tokens,
                  const float* __restrict__ pC,  const float* __restrict__ pEps,
                  const float* __restrict__ pV,  const float* __restrict__ pOsc,
                  const float* __restrict__ pGb, const float* __restrict__ pGs,
                  const float* __restrict__ pCa,
                  float* __restrict__ out,
                  float attn_scale, float omega, float phi)
{
    __shared__ float sKc[kL];
    __shared__ float sKs[kL];
    __shared__ float sVv[kL];

    constexpr int blocksPerSeq = kL / kTPerBlock;            // 512
    const int b     = blockIdx.x / blocksPerSeq;
    const int tbase = (blockIdx.x % blocksPerSeq) * kTPerBlock;
    const int sEnd  = tbase + kTPerBlock;                    // need s in [0, sEnd)

    const float c   = pC[0];
    const float eps = pEps[0];
    const float vsc = pV[0];
    const float osc = pOsc[0];
    const float ga  = pGb[0];
    const float gcs = pGs[0];
    const float cam = pCa[0];

    const int* tb = tokens + b * kL;

    // Stage per-s K/V arrays into LDS (recompute; no global scratch needed).
    for (int s = threadIdx.x; s < sEnd; s += kBlock) {
        const float df  = (float)tb[s];
        const float h0  = c - eps * df * df;
        const float h1  = -df;
        const float inv = rsqrtf(0.5f * (h0 * h0 + h1 * h1) + 1e-6f);
        const float hn0 = h0 * inv;
        const float hn1 = h1 * inv;
        const float r   = hn0 * rsqrtf(0.5f * hn0 * hn0 + 1e-6f);
        const float ang = omega * (float)(s % 19) + phi;     // exact mod-19 reduction
        float sn, cs;
        __sincosf(ang, &sn, &cs);
        sKc[s] = r * cs;
        sKs[s] = r * sn;
        sVv[s] = hn1 * vsc;
    }
    __syncthreads();

    const int wave = threadIdx.x >> 6;
    const int lane = threadIdx.x & 63;
    const int t    = tbase + wave;

    // Query-side values for this wave's t (uniform across lanes).
    const float df_t = (float)tb[t];
    const float h0   = c - eps * df_t * df_t;
    const float h1   = -df_t;
    const float invh = rsqrtf(0.5f * (h0 * h0 + h1 * h1) + 1e-6f);
    const float hn0  = h0 * invh;
    const float r_t  = hn0 * rsqrtf(0.5f * hn0 * hn0 + 1e-6f);
    float snt, cst;
    __sincosf(omega * (float)(t % 19), &snt, &cst);
    const float qc = attn_scale * r_t * cst;
    const float qs = attn_scale * r_t * snt;

    // Pass 1: max over s<=t (lanes stride the s range; LDS reads are broadcast-free).
    float m = -INFINITY;
    for (int s = lane; s <= t; s += 64) {
        const float x = fmaf(qc, sKc[s], qs * sKs[s]);
        m = fmaxf(m, x);
    }
    #pragma unroll
    for (int off = 32; off > 0; off >>= 1)
        m = fmaxf(m, __shfl_xor(m, off, 64));

    // Pass 2: exp-sum and weighted value sum.
    float sum = 0.0f, acc = 0.0f;
    for (int s = lane; s <= t; s += 64) {
        const float x = fmaf(qc, sKc[s], qs * sKs[s]);
        const float e = __expf(x - m);
        sum += e;
        acc = fmaf(e, sVv[s], acc);
    }
    #pragma unroll
    for (int off = 32; off > 0; off >>= 1) {
        sum += __shfl_xor(sum, off, 64);
        acc += __shfl_xor(acc, off, 64);
    }

    const float attn0 = acc / sum;

    // Epilogue (element-wise, all lanes compute identically).
    const float h1a  = h1 + osc * attn0;
    const float inv2 = rsqrtf(0.5f * (h0 * h0 + h1a * h1a) + 1e-6f);
    const float n0   = h0 * inv2;
    const float n1   = h1a * inv2;
    const float g0   = n0 * ga + n1 * gcs;
    const float g1   = n0 * (ga - gcs / c) + n1 * gcs;
    const float carry = cam * (fmaxf(g1, 0.0f) - fmaxf(g0, 0.0f)) * n0;
    const float h1b  = h1a + carry;
    const float inv3 = rsqrtf(0.5f * (h0 * h0 + h1b * h1b) + 1e-6f);
    const float rsq2 = 0.70710678118654752f;                 // 1/sqrt(2)
    const float o0   = h0  * inv3 * (0.1f * c * rsq2);
    const float o1   = h1b * inv3 * (-c * 0.02f * rsq2);     // -c/(50*sqrt(2))

    // out[b, t, j] = o0*tab[j,0] + o1*tab[j,1];  lanes 0..9 each write one j.
    if (lane < kVocab) {
        const float dj = (float)lane;
        out[(size_t)(b * kL + t) * kVocab + lane] =
            o0 * (c - eps * dj * dj) + o1 * (-dj);
    }
}

extern "C" void kernel_launch(void* const* d_in, const int* in_sizes, int n_in,
                              void* d_out, int out_size, void* d_ws, size_t ws_size,
                              hipStream_t stream)
{
    (void)in_sizes; (void)n_in; (void)d_ws; (void)ws_size; (void)out_size;

    const int*   tokens = (const int*)d_in[0];
    const float* C      = (const float*)d_in[1];
    const float* eps    = (const float*)d_in[2];
    const float* v      = (const float*)d_in[3];
    const float* o_sc   = (const float*)d_in[4];
    const float* g_base = (const float*)d_in[5];
    const float* g_slope= (const float*)d_in[6];
    const float* c_amp  = (const float*)d_in[7];

    // Host-side constant derivation (double precision).
    const double omega = 2.0 * M_PI / 19.0;
    const double amp   = log(10.0) / (cos(omega * 0.3) - cos(omega * 0.7));
    const float  attn_scale = (float)(amp * 0.5);   // (1/sqrt2) * (amp/sqrt2)
    const float  phi        = (float)(omega * 10.3);

    const dim3 grid(kB * kL / kTPerBlock);          // 8192 blocks
    fused_kernel<<<grid, kBlock, 0, stream>>>(
        tokens, C, eps, v, o_sc, g_base, g_slope, c_amp,
        (float*)d_out, attn_scale, (float)omega, phi);
}

// Round 2
// 75.253 us; speedup vs baseline: 1.3701x; 1.3701x over previous
//
#include <hip/hip_runtime.h>
#include <math.h>

#ifndef M_PI
#define M_PI 3.14159265358979323846
#endif

namespace {
constexpr int kL = 2048;          // sequence length
constexpr int kB = 16;            // batch
constexpr int kV = 10;            // vocab
constexpr int kChunk = 64;        // queries per block (lane-per-query)
constexpr int kBlock = 256;       // 4 waves split the bins
constexpr int kBins  = 192;       // 19 phases * 10 tokens = 190, padded to 192
constexpr int kBPW   = 48;        // bins per wave
constexpr int kChunksPerSeq = kL / kChunk;   // 32
}

// score(t,s) = A * r_t * r_s * cos(omega*(s-t)+phi) depends on s ONLY through
// bin(s) = (s mod 19)*10 + token_s  -- 190 bins. Softmax over s<=t collapses to
// a count-weighted 190-bin sum. Per block (one 64-query chunk):
//   - base histogram of s < t0 (cooperative LDS atomic counts)
//   - in-chunk inclusive counts via ballot + popcount(mask & lanes<=l)
//   - 4 waves each cover 48 bins; partial max/sum/acc combined through LDS
//   - lane l owns query t0+l end-to-end (q-side, epilogue, output) -- the
//     epilogue vectorizes across lanes, no per-query butterflies anywhere.

__global__ __launch_bounds__(kBlock)
void fused_kernel(const int* __restrict__ tokens,
                  const float* __restrict__ pC,  const float* __restrict__ pEps,
                  const float* __restrict__ pV,  const float* __restrict__ pOsc,
                  const float* __restrict__ pGb, const float* __restrict__ pGs,
                  const float* __restrict__ pCa,
                  float* __restrict__ out,
                  float A, float omega, float phi)
{
    __shared__ int   sCnt[kBins];
    __shared__ float sKc[kBins], sKs[kBins], sVv[kBins];
    __shared__ float sM[4][kChunk], sS[4][kChunk], sA[4][kChunk];

    const int tid  = threadIdx.x;
    const int w    = tid >> 6;
    const int lane = tid & 63;
    const int seq  = blockIdx.x / kChunksPerSeq;
    const int t0   = (blockIdx.x % kChunksPerSeq) * kChunk;
    const int* tok = tokens + seq * kL;

    const float c   = pC[0];
    const float eps = pEps[0];
    const float vsc = pV[0];
    const float osc = pOsc[0];
    const float ga  = pGb[0];
    const float gcs = pGs[0];
    const float cam = pCa[0];

    // ---- Bin tables: Kc[p,d] = r_d*cos(omega*p+phi), Ks, Vv[d] ----
    if (tid < kBins) {
        sCnt[tid] = 0;
        float kc = 0.f, ks = 0.f, vv = 0.f;
        if (tid < 190) {
            const int   p  = tid / 10;
            const float df = (float)(tid - p * 10);
            const float h0 = c - eps * df * df;
            const float h1 = -df;
            const float iv = rsqrtf(0.5f * (h0 * h0 + h1 * h1) + 1e-6f);
            const float n0 = h0 * iv;
            const float r  = n0 * rsqrtf(0.5f * n0 * n0 + 1e-6f);
            float sn, cs;
            __sincosf(omega * (float)p + phi, &sn, &cs);
            kc = r * cs; ks = r * sn; vv = (h1 * iv) * vsc;
        }
        sKc[tid] = kc; sKs[tid] = ks; sVv[tid] = vv;
    }
    __syncthreads();

    // ---- Base histogram over s < t0 ----
    for (int s = tid; s < t0; s += kBlock) {
        const int d = tok[s];
        const int p = s % 19;
        atomicAdd(&sCnt[p * 10 + d], 1);
    }
    __syncthreads();

    // ---- Per-lane query-side values (lane l <-> query t0+l) ----
    const int   t   = t0 + lane;
    const int   dt  = tok[t];
    const float dft = (float)dt;
    const float h0  = c - eps * dft * dft;
    const float h1  = -dft;
    const float ivh = rsqrtf(0.5f * (h0 * h0 + h1 * h1) + 1e-6f);
    const float hn0 = h0 * ivh;
    const float r_t = hn0 * rsqrtf(0.5f * hn0 * hn0 + 1e-6f);
    const int   pt  = t % 19;
    float snq, csq;
    __sincosf(omega * (float)pt, &snq, &csq);
    const float qc = A * r_t * csq;
    const float qs = A * r_t * snq;
    const int   mybin = pt * 10 + dt;
    const unsigned long long leInc =
        (lane == 63) ? ~0ull : ((1ull << (lane + 1)) - 1ull);

    const int blo = w * kBPW, bhi = blo + kBPW;

    // ---- Pass 1: exact masked max over this wave's bins ----
    float m = -INFINITY;
    #pragma unroll 8
    for (int bb = blo; bb < bhi; ++bb) {
        const unsigned long long msk = __ballot(mybin == bb);
        const int   cnt = sCnt[bb] + (int)__popcll(msk & leInc);
        const float sc  = fmaf(qc, sKc[bb], qs * sKs[bb]);
        m = fmaxf(m, (cnt > 0) ? sc : -INFINITY);
    }
    sM[w][lane] = m;
    __syncthreads();
    m = fmaxf(fmaxf(sM[0][lane], sM[1][lane]), fmaxf(sM[2][lane], sM[3][lane]));

    // ---- Pass 2: count-weighted exp accumulation ----
    float sum = 0.f, acc = 0.f;
    #pragma unroll 8
    for (int bb = blo; bb < bhi; ++bb) {
        const unsigned long long msk = __ballot(mybin == bb);
        const int   cnt = sCnt[bb] + (int)__popcll(msk & leInc);
        const float sc  = fmaf(qc, sKc[bb], qs * sKs[bb]);
        const float e   = (cnt > 0) ? __expf(sc - m) : 0.f;   // select, not mult: no inf*0
        const float ce  = (float)cnt * e;
        sum += ce;
        acc = fmaf(ce, sVv[bb], acc);
    }
    sS[w][lane] = sum;
    sA[w][lane] = acc;
    __syncthreads();

    // ---- Epilogue: wave 0, lane l finishes query t0+l ----
    if (w == 0) {
        sum = (sS[0][lane] + sS[1][lane]) + (sS[2][lane] + sS[3][lane]);
        acc = (sA[0][lane] + sA[1][lane]) + (sA[2][lane] + sA[3][lane]);
        const float attn0 = acc / sum;

        const float h1a  = h1 + osc * attn0;
        const float inv2 = rsqrtf(0.5f * (h0 * h0 + h1a * h1a) + 1e-6f);
        const float n0   = h0 * inv2;
        const float n1   = h1a * inv2;
        const float g0   = n0 * ga + n1 * gcs;
        const float g1   = n0 * (ga - gcs / c) + n1 * gcs;
        const float carry = cam * (fmaxf(g1, 0.0f) - fmaxf(g0, 0.0f)) * n0;
        const float h1b  = h1a + carry;
        const float inv3 = rsqrtf(0.5f * (h0 * h0 + h1b * h1b) + 1e-6f);
        const float rsq2 = 0.70710678118654752f;
        const float o0   = h0  * inv3 * (0.1f * c * rsq2);
        const float o1   = h1b * inv3 * (-c * 0.02f * rsq2);

        float* op = out + (size_t)(seq * kL + t) * kV;
        #pragma unroll
        for (int j = 0; j < kV; ++j) {
            const float dj = (float)j;
            op[j] = fmaf(o0, c - eps * dj * dj, o1 * (-dj));
        }
    }
}

extern "C" void kernel_launch(void* const* d_in, const int* in_sizes, int n_in,
                              void* d_out, int out_size, void* d_ws, size_t ws_size,
                              hipStream_t stream)
{
    (void)in_sizes; (void)n_in; (void)d_ws; (void)ws_size; (void)out_size;

    const int*   tokens = (const int*)d_in[0];
    const float* C      = (const float*)d_in[1];
    const float* eps    = (const float*)d_in[2];
    const float* v      = (const float*)d_in[3];
    const float* o_sc   = (const float*)d_in[4];
    const float* g_base = (const float*)d_in[5];
    const float* g_slope= (const float*)d_in[6];
    const float* c_amp  = (const float*)d_in[7];

    const double omega = 2.0 * M_PI / 19.0;
    const double amp   = log(10.0) / (cos(omega * 0.3) - cos(omega * 0.7));
    const float  attn_scale = (float)(amp * 0.5);   // (1/sqrt2)*(amp/sqrt2)
    const float  phi        = (float)(omega * 10.3);

    const dim3 grid(kB * kChunksPerSeq);            // 512 blocks
    fused_kernel<<<grid, kBlock, 0, stream>>>(
        tokens, C, eps, v, o_sc, g_base, g_slope, c_amp,
        (float*)d_out, attn_scale, (float)omega, phi);
}